// Round 1
// baseline (607.929 us; speedup 1.0000x reference)
//
#include <hip/hip_runtime.h>

// KPMiniMod: fused modulated kernel-point convolution.
// Inputs (f32 unless noted):
//  0 q_pts (32000,3) 1 s_pts (32000,3) 2 s_feats (32000,64) 3 neighb_inds (32000,32) int32
//  4 kernel_points (15,3) 5 weights (15,64) 6 w1 (64,64) 7 b1 (64) 8 w2 (64,120)
// Output: (32000,64) f32.

#define MQ 32000

__device__ __forceinline__ float rlf(float v, int l) {
    return __int_as_float(__builtin_amdgcn_readlane(__float_as_int(v), l));
}
__device__ __forceinline__ int rli(int v, int l) {
    return __builtin_amdgcn_readlane(v, l);
}

__global__ __launch_bounds__(256, 3)
void kpconv_fused(const float* __restrict__ q_pts,
                  const float* __restrict__ s_pts,
                  const float* __restrict__ s_feats,
                  const int*   __restrict__ neighb_inds,
                  const float* __restrict__ kpts,
                  const float* __restrict__ weights,
                  const float* __restrict__ w1,
                  const float* __restrict__ b1,
                  const float* __restrict__ w2,
                  float* __restrict__ out)
{
    __shared__ float w1_lds[64 * 64];        // 16 KB
    __shared__ float w2_lds[64 * 120 + 8];   // 30.75 KB (+pad so j=64+c reads stay in-bounds)
    __shared__ float wt_lds[15 * 64];        // 3.75 KB

    const int tid = threadIdx.x;
    {   // cooperative table staging (float4, coalesced)
        const float4* s1 = (const float4*)w1;
        float4* d1 = (float4*)w1_lds;
        #pragma unroll
        for (int i = 0; i < 4; ++i) d1[tid + 256 * i] = s1[tid + 256 * i];
        const float4* s2 = (const float4*)w2;
        float4* d2 = (float4*)w2_lds;
        for (int i = tid; i < (64 * 120) / 4; i += 256) d2[i] = s2[i];
        const float4* s3 = (const float4*)weights;
        float4* d3 = (float4*)wt_lds;
        if (tid < 240) d3[tid] = s3[tid];
        if (tid < 8) w2_lds[64 * 120 + tid] = 0.f;
    }
    __syncthreads();

    const int lane = tid & 63;
    const int wid  = tid >> 6;
    const int c    = lane;
    const int u    = c >> 3;                  // channel-group index (GROUPS=8)
    const int nwaves = gridDim.x * 4;
    const int gwave  = blockIdx.x * 4 + wid;

    const float b1v = b1[c];
    const int cB = 64 + ((c < 56) ? c : 55);  // second layer-2 output slot (c>=56 unused)

    for (int pair = gwave; pair * 2 < MQ; pair += nwaves) {
        const int m0 = pair * 2;

        // ---------------- MLP layer 1: h = leaky(f @ w1 + b1) ----------------
        float f0 = s_feats[(size_t)m0 * 64 + c];
        float f1 = s_feats[(size_t)(m0 + 1) * 64 + c];
        float h0 = b1v, h1 = b1v;
        #pragma unroll
        for (int i = 0; i < 64; ++i) {
            float w = w1_lds[i * 64 + c];
            h0 = fmaf(rlf(f0, i), w, h0);
            h1 = fmaf(rlf(f1, i), w, h1);
        }
        h0 = (h0 >= 0.f) ? h0 : 0.1f * h0;
        h1 = (h1 >= 0.f) ? h1 : 0.1f * h1;

        // ---------------- MLP layer 2: mod = sigmoid(h @ w2) -----------------
        float a00 = 0.f, a01 = 0.f, a10 = 0.f, a11 = 0.f;
        #pragma unroll
        for (int i = 0; i < 64; ++i) {
            float wA = w2_lds[i * 120 + c];   // j = c
            float wB = w2_lds[i * 120 + cB];  // j = 64 + c (c<56)
            float s0 = rlf(h0, i);
            float s1 = rlf(h1, i);
            a00 = fmaf(s0, wA, a00);
            a01 = fmaf(s0, wB, a01);
            a10 = fmaf(s1, wA, a10);
            a11 = fmaf(s1, wB, a11);
        }
        const float sA0 = 1.f / (1.f + __expf(-a00));  // sig[j=c], query m0
        const float sB0 = 1.f / (1.f + __expf(-a01));  // sig[j=64+c]
        const float sA1 = 1.f / (1.f + __expf(-a10));
        const float sB1 = 1.f / (1.f + __expf(-a11));

        // -------- influence: lane = q*32 + h handles neighbor h of query m0+q --------
        const int q = lane >> 5;
        const int m = m0 + q;
        const int ind = neighb_inds[(size_t)m0 * 32 + lane];  // coalesced 64 ints
        const float qx = q_pts[m * 3 + 0];
        const float qy = q_pts[m * 3 + 1];
        const float qz = q_pts[m * 3 + 2];
        const float px = s_pts[(size_t)ind * 3 + 0] - qx;
        const float py = s_pts[(size_t)ind * 3 + 1] - qy;
        const float pz = s_pts[(size_t)ind * 3 + 2] - qz;
        float best = 1e30f; int bk = 0;
        #pragma unroll
        for (int k = 0; k < 15; ++k) {        // kernel_points -> SGPR scalar loads
            float ex = px - kpts[k * 3 + 0];
            float ey = py - kpts[k * 3 + 1];
            float ez = pz - kpts[k * 3 + 2];
            float d2 = fmaf(ex, ex, fmaf(ey, ey, ez * ez));
            if (d2 < best) { best = d2; bk = k; }  // strict < keeps first (argmin tie rule)
        }
        const float infl = fmaxf(0.f, 1.f - sqrtf(best));  // SIGMA = 1

        // -------- aggregate: out[m,c] = sum_h feat[ind_h,c] * infl_h * W[k_h,c] * sig[k_h*8+u] --------
        float acc0 = 0.f, acc1 = 0.f;
        #pragma unroll
        for (int h = 0; h < 32; ++h) {
            {   // query m0  (scalars live on lanes 0..31)
                const int   ih = rli(ind, h);        // SGPR -> scalar-base gather
                const int   kh = rli(bk, h);
                const float fl = rlf(infl, h);
                const int idx = kh * 8 + u;
                const float sv = (kh < 8) ? __shfl(sA0, idx) : __shfl(sB0, idx - 64);
                const float w = wt_lds[kh * 64 + c] * sv * fl;
                acc0 = fmaf(s_feats[(size_t)ih * 64 + c], w, acc0);
            }
            {   // query m0+1 (scalars live on lanes 32..63)
                const int   ih = rli(ind, 32 + h);
                const int   kh = rli(bk, 32 + h);
                const float fl = rlf(infl, 32 + h);
                const int idx = kh * 8 + u;
                const float sv = (kh < 8) ? __shfl(sA1, idx) : __shfl(sB1, idx - 64);
                const float w = wt_lds[kh * 64 + c] * sv * fl;
                acc1 = fmaf(s_feats[(size_t)ih * 64 + c], w, acc1);
            }
        }
        out[(size_t)m0 * 64 + c]       = acc0;
        out[(size_t)(m0 + 1) * 64 + c] = acc1;
    }
}

extern "C" void kernel_launch(void* const* d_in, const int* in_sizes, int n_in,
                              void* d_out, int out_size, void* d_ws, size_t ws_size,
                              hipStream_t stream) {
    const float* q_pts       = (const float*)d_in[0];
    const float* s_pts       = (const float*)d_in[1];
    const float* s_feats     = (const float*)d_in[2];
    const int*   neighb_inds = (const int*)d_in[3];
    const float* kpts        = (const float*)d_in[4];
    const float* weights     = (const float*)d_in[5];
    const float* w1          = (const float*)d_in[6];
    const float* b1          = (const float*)d_in[7];
    const float* w2          = (const float*)d_in[8];
    float* out = (float*)d_out;

    // 3 blocks/CU (LDS-capped) x 256 CUs; grid-stride pair loop inside.
    kpconv_fused<<<768, 256, 0, stream>>>(q_pts, s_pts, s_feats, neighb_inds,
                                          kpts, weights, w1, b1, w2, out);
}

// Round 2
// 430.171 us; speedup vs baseline: 1.4132x; 1.4132x over previous
//
#include <hip/hip_runtime.h>

// KPMiniMod: fused modulated kernel-point convolution.
// Round 2: batched gather (32-deep MLP per query) — the aggregate phase now
// issues all 32 row-gathers into registers before the fma reduction, instead
// of a serial load->fma->load chain (~2 outstanding). Latency-bound fix.

#define MQ 32000

__device__ __forceinline__ float rlf(float v, int l) {
    return __int_as_float(__builtin_amdgcn_readlane(__float_as_int(v), l));
}
__device__ __forceinline__ int rli(int v, int l) {
    return __builtin_amdgcn_readlane(v, l);
}

__global__ __launch_bounds__(256, 3)
void kpconv_fused(const float* __restrict__ q_pts,
                  const float* __restrict__ s_pts,
                  const float* __restrict__ s_feats,
                  const int*   __restrict__ neighb_inds,
                  const float* __restrict__ kpts,
                  const float* __restrict__ weights,
                  const float* __restrict__ w1,
                  const float* __restrict__ b1,
                  const float* __restrict__ w2,
                  float* __restrict__ out)
{
    __shared__ float w1_lds[64 * 64];        // 16 KB
    __shared__ float w2_lds[64 * 120 + 8];   // 30.75 KB
    __shared__ float wt_lds[15 * 64];        // 3.75 KB

    const int tid = threadIdx.x;
    {   // cooperative table staging (float4, coalesced)
        const float4* s1 = (const float4*)w1;
        float4* d1 = (float4*)w1_lds;
        #pragma unroll
        for (int i = 0; i < 4; ++i) d1[tid + 256 * i] = s1[tid + 256 * i];
        const float4* s2 = (const float4*)w2;
        float4* d2 = (float4*)w2_lds;
        for (int i = tid; i < (64 * 120) / 4; i += 256) d2[i] = s2[i];
        const float4* s3 = (const float4*)weights;
        float4* d3 = (float4*)wt_lds;
        if (tid < 240) d3[tid] = s3[tid];
        if (tid < 8) w2_lds[64 * 120 + tid] = 0.f;
    }
    __syncthreads();

    const int lane = tid & 63;
    const int wid  = tid >> 6;
    const int c    = lane;
    const int u    = c >> 3;                  // channel-group (GROUPS=8)
    const int nwaves = gridDim.x * 4;
    const int gwave  = blockIdx.x * 4 + wid;

    const float b1v = b1[c];
    const int cB = 64 + ((c < 56) ? c : 55);  // layer-2 second output slot (c>=56 unused)

    for (int pair = gwave; pair * 2 < MQ; pair += nwaves) {
        const int m0 = pair * 2;

        // ---------------- MLP layer 1: h = leaky(f @ w1 + b1) ----------------
        float f0 = s_feats[(size_t)m0 * 64 + c];
        float f1 = s_feats[(size_t)(m0 + 1) * 64 + c];
        float h0a = b1v, h0b = 0.f, h1a = b1v, h1b = 0.f;
        #pragma unroll
        for (int i = 0; i < 64; i += 2) {
            float wa = w1_lds[i * 64 + c];
            float wb = w1_lds[(i + 1) * 64 + c];
            h0a = fmaf(rlf(f0, i), wa, h0a);
            h0b = fmaf(rlf(f0, i + 1), wb, h0b);
            h1a = fmaf(rlf(f1, i), wa, h1a);
            h1b = fmaf(rlf(f1, i + 1), wb, h1b);
        }
        float h0 = h0a + h0b, h1 = h1a + h1b;
        h0 = (h0 >= 0.f) ? h0 : 0.1f * h0;
        h1 = (h1 >= 0.f) ? h1 : 0.1f * h1;

        // ---------------- MLP layer 2: mod = sigmoid(h @ w2) -----------------
        float a00 = 0.f, a01 = 0.f, a10 = 0.f, a11 = 0.f;
        #pragma unroll
        for (int i = 0; i < 64; ++i) {
            float wA = w2_lds[i * 120 + c];   // j = c
            float wB = w2_lds[i * 120 + cB];  // j = 64 + c (c<56)
            float s0 = rlf(h0, i);
            float s1 = rlf(h1, i);
            a00 = fmaf(s0, wA, a00);
            a01 = fmaf(s0, wB, a01);
            a10 = fmaf(s1, wA, a10);
            a11 = fmaf(s1, wB, a11);
        }
        const float sA0 = 1.f / (1.f + __expf(-a00));
        const float sB0 = 1.f / (1.f + __expf(-a01));
        const float sA1 = 1.f / (1.f + __expf(-a10));
        const float sB1 = 1.f / (1.f + __expf(-a11));

        // -------- influence: lane = q*32 + h -> neighbor h of query m0+q --------
        const int q = lane >> 5;
        const int m = m0 + q;
        const int ind = neighb_inds[(size_t)m0 * 32 + lane];  // coalesced
        const float qx = q_pts[m * 3 + 0];
        const float qy = q_pts[m * 3 + 1];
        const float qz = q_pts[m * 3 + 2];
        const float px = s_pts[(size_t)ind * 3 + 0] - qx;
        const float py = s_pts[(size_t)ind * 3 + 1] - qy;
        const float pz = s_pts[(size_t)ind * 3 + 2] - qz;
        float best = 1e30f; int bk = 0;
        #pragma unroll
        for (int k = 0; k < 15; ++k) {        // kpts -> uniform SGPR loads
            float ex = px - kpts[k * 3 + 0];
            float ey = py - kpts[k * 3 + 1];
            float ez = pz - kpts[k * 3 + 2];
            float d2 = fmaf(ex, ex, fmaf(ey, ey, ez * ez));
            if (d2 < best) { best = d2; bk = k; }  // strict < = first-min (argmin rule)
        }
        const float infl = fmaxf(0.f, 1.f - sqrtf(best));  // SIGMA = 1
        const int pk = (ind << 4) | bk;       // pack for single readlane

        // -------- aggregate, batched: 32 gathers in flight, then reduce --------
        float acc0, acc1;
        {   // query m0 (scalars on lanes 0..31)
            float fv[32], wv[32];
            #pragma unroll
            for (int h = 0; h < 32; ++h) {
                const int   s  = rli(pk, h);
                const float fl = rlf(infl, h);
                const int   kh = s & 15;
                const int   ih = s >> 4;
                const float sv = __shfl((kh < 8) ? sA0 : sB0, ((kh & 7) << 3) + u);
                wv[h] = wt_lds[(kh << 6) + c] * sv * fl;
                fv[h] = s_feats[(size_t)ih * 64 + c];
            }
            float p0 = 0.f, p1 = 0.f, p2 = 0.f, p3 = 0.f;
            #pragma unroll
            for (int h = 0; h < 32; h += 4) {
                p0 = fmaf(fv[h + 0], wv[h + 0], p0);
                p1 = fmaf(fv[h + 1], wv[h + 1], p1);
                p2 = fmaf(fv[h + 2], wv[h + 2], p2);
                p3 = fmaf(fv[h + 3], wv[h + 3], p3);
            }
            acc0 = (p0 + p1) + (p2 + p3);
        }
        {   // query m0+1 (scalars on lanes 32..63)
            float fv[32], wv[32];
            #pragma unroll
            for (int h = 0; h < 32; ++h) {
                const int   s  = rli(pk, 32 + h);
                const float fl = rlf(infl, 32 + h);
                const int   kh = s & 15;
                const int   ih = s >> 4;
                const float sv = __shfl((kh < 8) ? sA1 : sB1, ((kh & 7) << 3) + u);
                wv[h] = wt_lds[(kh << 6) + c] * sv * fl;
                fv[h] = s_feats[(size_t)ih * 64 + c];
            }
            float p0 = 0.f, p1 = 0.f, p2 = 0.f, p3 = 0.f;
            #pragma unroll
            for (int h = 0; h < 32; h += 4) {
                p0 = fmaf(fv[h + 0], wv[h + 0], p0);
                p1 = fmaf(fv[h + 1], wv[h + 1], p1);
                p2 = fmaf(fv[h + 2], wv[h + 2], p2);
                p3 = fmaf(fv[h + 3], wv[h + 3], p3);
            }
            acc1 = (p0 + p1) + (p2 + p3);
        }
        out[(size_t)m0 * 64 + c]       = acc0;
        out[(size_t)(m0 + 1) * 64 + c] = acc1;
    }
}

extern "C" void kernel_launch(void* const* d_in, const int* in_sizes, int n_in,
                              void* d_out, int out_size, void* d_ws, size_t ws_size,
                              hipStream_t stream) {
    const float* q_pts       = (const float*)d_in[0];
    const float* s_pts       = (const float*)d_in[1];
    const float* s_feats     = (const float*)d_in[2];
    const int*   neighb_inds = (const int*)d_in[3];
    const float* kpts        = (const float*)d_in[4];
    const float* weights     = (const float*)d_in[5];
    const float* b1          = (const float*)d_in[6 + 1 - 1 + 1 - 1 + 1];  // placeholder avoided below
    (void)b1;
    const float* w1          = (const float*)d_in[6];
    const float* b1_         = (const float*)d_in[7];
    const float* w2          = (const float*)d_in[8];
    float* out = (float*)d_out;

    // 3 blocks/CU (LDS 50.5 KB) x 256 CUs resident; grid-stride pair loop.
    kpconv_fused<<<768, 256, 0, stream>>>(q_pts, s_pts, s_feats, neighb_inds,
                                          kpts, weights, w1, b1_, w2, out);
}

// Round 4
// 392.649 us; speedup vs baseline: 1.5483x; 1.0956x over previous
//
#include <hip/hip_runtime.h>

// KPMiniMod round 3 (resubmit after infra failure): two-kernel split.
//  Phase 1 (mod_mlp): modulations sigmoid(leaky(f@w1+b1)@w2) for all M -> d_ws (M x 120 f32).
//  Phase 2 (kp_gather): influence + deep-batched random row gathers + aggregate.
//  Rationale: round-2 counters showed VGPR=84 (compiler kept only ~8-12 gathers
//  in flight; lgkm ops interleaved with loads) and occupancy LDS-capped at 32%.
//  Phase 2 has pure-load batches (readlane-addressed) and only 3.75 KB LDS.

#define MQ 32000

__device__ __forceinline__ float rlf(float v, int l) {
    return __int_as_float(__builtin_amdgcn_readlane(__float_as_int(v), l));
}
__device__ __forceinline__ int rli(int v, int l) {
    return __builtin_amdgcn_readlane(v, l);
}

// ---------------------------------------------------------------- phase 1
__global__ __launch_bounds__(256, 3)
void mod_mlp(const float* __restrict__ s_feats,
             const float* __restrict__ w1,
             const float* __restrict__ b1,
             const float* __restrict__ w2,
             float* __restrict__ modw)   // (M,120) sigmoid already applied
{
    __shared__ float w1_lds[64 * 64];       // 16 KB
    __shared__ float w2_lds[64 * 120 + 8];  // 30.75 KB

    const int tid = threadIdx.x;
    {
        const float4* s1 = (const float4*)w1;
        float4* d1 = (float4*)w1_lds;
        #pragma unroll
        for (int i = 0; i < 4; ++i) d1[tid + 256 * i] = s1[tid + 256 * i];
        const float4* s2 = (const float4*)w2;
        float4* d2 = (float4*)w2_lds;
        for (int i = tid; i < (64 * 120) / 4; i += 256) d2[i] = s2[i];
        if (tid < 8) w2_lds[64 * 120 + tid] = 0.f;
    }
    __syncthreads();

    const int lane = tid & 63;
    const int wid  = tid >> 6;
    const int c    = lane;
    const int nwaves = gridDim.x * 4;
    const int gwave  = blockIdx.x * 4 + wid;

    const float b1v = b1[c];
    const int cB = 64 + ((c < 56) ? c : 55);   // c>=56: dummy slot, not stored

    for (int pair = gwave; pair * 2 < MQ; pair += nwaves) {
        const int m0 = pair * 2;
        float f0 = s_feats[(size_t)m0 * 64 + c];
        float f1 = s_feats[(size_t)(m0 + 1) * 64 + c];
        float h0a = b1v, h0b = 0.f, h1a = b1v, h1b = 0.f;
        #pragma unroll
        for (int i = 0; i < 64; i += 2) {
            float wa = w1_lds[i * 64 + c];
            float wb = w1_lds[(i + 1) * 64 + c];
            h0a = fmaf(rlf(f0, i), wa, h0a);
            h0b = fmaf(rlf(f0, i + 1), wb, h0b);
            h1a = fmaf(rlf(f1, i), wa, h1a);
            h1b = fmaf(rlf(f1, i + 1), wb, h1b);
        }
        float h0 = h0a + h0b, h1 = h1a + h1b;
        h0 = (h0 >= 0.f) ? h0 : 0.1f * h0;
        h1 = (h1 >= 0.f) ? h1 : 0.1f * h1;

        float a00 = 0.f, a01 = 0.f, a10 = 0.f, a11 = 0.f;
        #pragma unroll
        for (int i = 0; i < 64; ++i) {
            float wA = w2_lds[i * 120 + c];
            float wB = w2_lds[i * 120 + cB];
            float s0 = rlf(h0, i);
            float s1 = rlf(h1, i);
            a00 = fmaf(s0, wA, a00);
            a01 = fmaf(s0, wB, a01);
            a10 = fmaf(s1, wA, a10);
            a11 = fmaf(s1, wB, a11);
        }
        modw[(size_t)m0 * 120 + c]       = 1.f / (1.f + __expf(-a00));
        modw[(size_t)(m0 + 1) * 120 + c] = 1.f / (1.f + __expf(-a10));
        if (c < 56) {
            modw[(size_t)m0 * 120 + 64 + c]       = 1.f / (1.f + __expf(-a01));
            modw[(size_t)(m0 + 1) * 120 + 64 + c] = 1.f / (1.f + __expf(-a11));
        }
    }
}

// ---------------------------------------------------------------- phase 2
__global__ __launch_bounds__(256, 4)
void kp_gather(const float* __restrict__ q_pts,
               const float* __restrict__ s_pts,
               const float* __restrict__ s_feats,
               const int*   __restrict__ neighb_inds,
               const float* __restrict__ kpts,
               const float* __restrict__ weights,
               const float* __restrict__ modw,
               float* __restrict__ out)
{
    __shared__ float wt_lds[15 * 64];   // 3.75 KB only
    const int tid = threadIdx.x;
    if (tid < 240) ((float4*)wt_lds)[tid] = ((const float4*)weights)[tid];
    __syncthreads();

    const int lane = tid & 63;
    const int wid  = tid >> 6;
    const int c    = lane;
    const int u    = c >> 3;
    const int pair = blockIdx.x * 4 + wid;   // grid sized exactly: 16000 pairs
    const int m0 = pair * 2;

    // ---- influence: lane = q*32 + h handles neighbor h of query m0+q ----
    const int q = lane >> 5;
    const int m = m0 + q;
    const int ind = neighb_inds[(size_t)m0 * 32 + lane];   // coalesced 64 ints
    const float qx = q_pts[m * 3 + 0];
    const float qy = q_pts[m * 3 + 1];
    const float qz = q_pts[m * 3 + 2];
    const float px = s_pts[(size_t)ind * 3 + 0] - qx;
    const float py = s_pts[(size_t)ind * 3 + 1] - qy;
    const float pz = s_pts[(size_t)ind * 3 + 2] - qz;
    float best = 1e30f; int bk = 0;
    #pragma unroll
    for (int k = 0; k < 15; ++k) {            // kpts -> uniform SGPR loads
        float ex = px - kpts[k * 3 + 0];
        float ey = py - kpts[k * 3 + 1];
        float ez = pz - kpts[k * 3 + 2];
        float d2 = fmaf(ex, ex, fmaf(ey, ey, ez * ez));
        if (d2 < best) { best = d2; bk = k; } // strict < = first-min (argmin rule)
    }
    const float infl = fmaxf(0.f, 1.f - sqrtf(best));   // SIGMA = 1
    const int pk = (ind << 4) | bk;

    // ---- modulation rows (sigmoid pre-applied): lane c holds slots c and 64+c ----
    const size_t mb0 = (size_t)m0 * 120, mb1 = mb0 + 120;
    const float vA0 = modw[mb0 + c];
    const float vB0 = (c < 56) ? modw[mb0 + 64 + c] : 0.f;
    const float vA1 = modw[mb1 + c];
    const float vB1 = (c < 56) ? modw[mb1 + 64 + c] : 0.f;

    // ---- deep-batched gathers: pure loads, addresses via readlane only ----
    float fv0[32], fv1[32];
    #pragma unroll
    for (int h = 0; h < 32; ++h)
        fv0[h] = s_feats[(size_t)(rli(pk, h) >> 4) * 64 + c];
    #pragma unroll
    for (int h = 0; h < 32; ++h)
        fv1[h] = s_feats[(size_t)(rli(pk, 32 + h) >> 4) * 64 + c];

    // ---- reduce query m0 ----
    float p0 = 0.f, p1 = 0.f, p2 = 0.f, p3 = 0.f;
    #pragma unroll
    for (int h = 0; h < 32; h += 4) {
        #pragma unroll
        for (int j = 0; j < 4; ++j) {
            const int s = rli(pk, h + j);
            const int kh = s & 15;
            const float fl = rlf(infl, h + j);
            const float sv = (kh < 8) ? __shfl(vA0, (kh << 3) + u)
                                      : __shfl(vB0, ((kh - 8) << 3) + u);
            const float w = wt_lds[(kh << 6) + c] * sv * fl;
            float& p = (j == 0) ? p0 : (j == 1) ? p1 : (j == 2) ? p2 : p3;
            p = fmaf(fv0[h + j], w, p);
        }
    }
    const float acc0 = (p0 + p1) + (p2 + p3);

    // ---- reduce query m0+1 ----
    float r0 = 0.f, r1 = 0.f, r2 = 0.f, r3 = 0.f;
    #pragma unroll
    for (int h = 0; h < 32; h += 4) {
        #pragma unroll
        for (int j = 0; j < 4; ++j) {
            const int s = rli(pk, 32 + h + j);
            const int kh = s & 15;
            const float fl = rlf(infl, 32 + h + j);
            const float sv = (kh < 8) ? __shfl(vA1, (kh << 3) + u)
                                      : __shfl(vB1, ((kh - 8) << 3) + u);
            const float w = wt_lds[(kh << 6) + c] * sv * fl;
            float& p = (j == 0) ? r0 : (j == 1) ? r1 : (j == 2) ? r2 : r3;
            p = fmaf(fv1[h + j], w, p);
        }
    }
    const float acc1 = (r0 + r1) + (r2 + r3);

    out[(size_t)m0 * 64 + c]       = acc0;
    out[(size_t)(m0 + 1) * 64 + c] = acc1;
}

// ------------------------- fallback (round-2 fused), only if ws too small
__global__ __launch_bounds__(256, 3)
void kpconv_fused(const float* __restrict__ q_pts, const float* __restrict__ s_pts,
                  const float* __restrict__ s_feats, const int* __restrict__ neighb_inds,
                  const float* __restrict__ kpts, const float* __restrict__ weights,
                  const float* __restrict__ w1, const float* __restrict__ b1,
                  const float* __restrict__ w2, float* __restrict__ out)
{
    __shared__ float w1_lds[64 * 64];
    __shared__ float w2_lds[64 * 120 + 8];
    __shared__ float wt_lds[15 * 64];
    const int tid = threadIdx.x;
    {
        const float4* s1 = (const float4*)w1; float4* d1 = (float4*)w1_lds;
        #pragma unroll
        for (int i = 0; i < 4; ++i) d1[tid + 256 * i] = s1[tid + 256 * i];
        const float4* s2 = (const float4*)w2; float4* d2 = (float4*)w2_lds;
        for (int i = tid; i < (64 * 120) / 4; i += 256) d2[i] = s2[i];
        const float4* s3 = (const float4*)weights; float4* d3 = (float4*)wt_lds;
        if (tid < 240) d3[tid] = s3[tid];
        if (tid < 8) w2_lds[64 * 120 + tid] = 0.f;
    }
    __syncthreads();
    const int lane = tid & 63, wid = tid >> 6, c = lane, u = c >> 3;
    const int nwaves = gridDim.x * 4, gwave = blockIdx.x * 4 + wid;
    const float b1v = b1[c];
    const int cB = 64 + ((c < 56) ? c : 55);
    for (int pair = gwave; pair * 2 < MQ; pair += nwaves) {
        const int m0 = pair * 2;
        float f0 = s_feats[(size_t)m0 * 64 + c];
        float f1 = s_feats[(size_t)(m0 + 1) * 64 + c];
        float h0 = b1v, h1 = b1v;
        #pragma unroll
        for (int i = 0; i < 64; ++i) {
            float w = w1_lds[i * 64 + c];
            h0 = fmaf(rlf(f0, i), w, h0);
            h1 = fmaf(rlf(f1, i), w, h1);
        }
        h0 = (h0 >= 0.f) ? h0 : 0.1f * h0;
        h1 = (h1 >= 0.f) ? h1 : 0.1f * h1;
        float a00 = 0.f, a01 = 0.f, a10 = 0.f, a11 = 0.f;
        #pragma unroll
        for (int i = 0; i < 64; ++i) {
            float wA = w2_lds[i * 120 + c], wB = w2_lds[i * 120 + cB];
            float s0 = rlf(h0, i), s1 = rlf(h1, i);
            a00 = fmaf(s0, wA, a00); a01 = fmaf(s0, wB, a01);
            a10 = fmaf(s1, wA, a10); a11 = fmaf(s1, wB, a11);
        }
        const float sA0 = 1.f / (1.f + __expf(-a00)), sB0 = 1.f / (1.f + __expf(-a01));
        const float sA1 = 1.f / (1.f + __expf(-a10)), sB1 = 1.f / (1.f + __expf(-a11));
        const int qq = lane >> 5, m = m0 + qq;
        const int ind = neighb_inds[(size_t)m0 * 32 + lane];
        const float qx = q_pts[m * 3], qy = q_pts[m * 3 + 1], qz = q_pts[m * 3 + 2];
        const float px = s_pts[(size_t)ind * 3] - qx;
        const float py = s_pts[(size_t)ind * 3 + 1] - qy;
        const float pz = s_pts[(size_t)ind * 3 + 2] - qz;
        float best = 1e30f; int bk = 0;
        #pragma unroll
        for (int k = 0; k < 15; ++k) {
            float ex = px - kpts[k * 3], ey = py - kpts[k * 3 + 1], ez = pz - kpts[k * 3 + 2];
            float d2 = fmaf(ex, ex, fmaf(ey, ey, ez * ez));
            if (d2 < best) { best = d2; bk = k; }
        }
        const float infl = fmaxf(0.f, 1.f - sqrtf(best));
        const int pk = (ind << 4) | bk;
        float acc0, acc1;
        {
            float fv[32], wv[32];
            #pragma unroll
            for (int h = 0; h < 32; ++h) {
                const int s = rli(pk, h); const float fl = rlf(infl, h);
                const int kh = s & 15, ih = s >> 4;
                const float sv = __shfl((kh < 8) ? sA0 : sB0, ((kh & 7) << 3) + u);
                wv[h] = wt_lds[(kh << 6) + c] * sv * fl;
                fv[h] = s_feats[(size_t)ih * 64 + c];
            }
            float p0 = 0, p1 = 0, p2 = 0, p3 = 0;
            #pragma unroll
            for (int h = 0; h < 32; h += 4) {
                p0 = fmaf(fv[h], wv[h], p0); p1 = fmaf(fv[h + 1], wv[h + 1], p1);
                p2 = fmaf(fv[h + 2], wv[h + 2], p2); p3 = fmaf(fv[h + 3], wv[h + 3], p3);
            }
            acc0 = (p0 + p1) + (p2 + p3);
        }
        {
            float fv[32], wv[32];
            #pragma unroll
            for (int h = 0; h < 32; ++h) {
                const int s = rli(pk, 32 + h); const float fl = rlf(infl, 32 + h);
                const int kh = s & 15, ih = s >> 4;
                const float sv = __shfl((kh < 8) ? sA1 : sB1, ((kh & 7) << 3) + u);
                wv[h] = wt_lds[(kh << 6) + c] * sv * fl;
                fv[h] = s_feats[(size_t)ih * 64 + c];
            }
            float p0 = 0, p1 = 0, p2 = 0, p3 = 0;
            #pragma unroll
            for (int h = 0; h < 32; h += 4) {
                p0 = fmaf(fv[h], wv[h], p0); p1 = fmaf(fv[h + 1], wv[h + 1], p1);
                p2 = fmaf(fv[h + 2], wv[h + 2], p2); p3 = fmaf(fv[h + 3], wv[h + 3], p3);
            }
            acc1 = (p0 + p1) + (p2 + p3);
        }
        out[(size_t)m0 * 64 + c] = acc0;
        out[(size_t)(m0 + 1) * 64 + c] = acc1;
    }
}

extern "C" void kernel_launch(void* const* d_in, const int* in_sizes, int n_in,
                              void* d_out, int out_size, void* d_ws, size_t ws_size,
                              hipStream_t stream) {
    const float* q_pts       = (const float*)d_in[0];
    const float* s_pts       = (const float*)d_in[1];
    const float* s_feats     = (const float*)d_in[2];
    const int*   neighb_inds = (const int*)d_in[3];
    const float* kpts        = (const float*)d_in[4];
    const float* weights     = (const float*)d_in[5];
    const float* w1          = (const float*)d_in[6];
    const float* b1          = (const float*)d_in[7];
    const float* w2          = (const float*)d_in[8];
    float* out = (float*)d_out;

    const size_t need = (size_t)MQ * 120 * sizeof(float);   // 15.36 MB
    if (ws_size >= need) {
        float* modw = (float*)d_ws;
        mod_mlp<<<768, 256, 0, stream>>>(s_feats, w1, b1, w2, modw);
        kp_gather<<<(MQ / 2 + 3) / 4, 256, 0, stream>>>(q_pts, s_pts, s_feats,
                                                        neighb_inds, kpts, weights,
                                                        modw, out);
    } else {
        kpconv_fused<<<768, 256, 0, stream>>>(q_pts, s_pts, s_feats, neighb_inds,
                                              kpts, weights, w1, b1, w2, out);
    }
}

// Round 5
// 234.575 us; speedup vs baseline: 2.5916x; 1.6739x over previous
//
#include <hip/hip_runtime.h>

// KPMiniMod round 5:
//  Phase 1 (mod_mlp_mfma): bf16 MFMA GEMM for the modulation MLP (was ~200us of
//    readlane-VALU work) -> modw (M x 120 f32) in ws; ALSO writes a bf16 copy of
//    s_feats (M x 64, 4.1 MB ~= one XCD L2) for the gather phase.
//  Phase 2 (kp_gather_bf16): influence + deep-batched random row gathers from the
//    bf16 table (halves gather bytes, mostly L2 hits) + aggregate.
//  Fallback: round-3/4 proven f32 path if ws is too small for fb+modw.

#define MQ 32000

typedef unsigned short u16;
typedef unsigned int   u32;
typedef __attribute__((ext_vector_type(8))) short bf16x8;  // 8 bf16 in 4 VGPRs
typedef __attribute__((ext_vector_type(4))) float f32x4;

__device__ __forceinline__ float rlf(float v, int l) {
    return __int_as_float(__builtin_amdgcn_readlane(__float_as_int(v), l));
}
__device__ __forceinline__ int rli(int v, int l) {
    return __builtin_amdgcn_readlane(v, l);
}
__device__ __forceinline__ u16 f2bf(float x) {   // f32 -> bf16 RTNE
    u32 u = __float_as_uint(x);
    return (u16)((u + 0x7FFFu + ((u >> 16) & 1u)) >> 16);
}
__device__ __forceinline__ float bf2f(u16 b) {
    return __uint_as_float(((u32)b) << 16);
}

// ---------------------------------------------------------------- phase 1 (MFMA)
// Per wave: 16 query rows. A row = lane&15, k = (lane>>4)*8+[0..8). B col = lane&15,
// k same. C/D: col = lane&15, row = (lane>>4)*4+reg  [m89-verified layout].
__global__ __launch_bounds__(256, 2)
void mod_mlp_mfma(const float* __restrict__ s_feats,
                  const float* __restrict__ w1,
                  const float* __restrict__ b1,
                  const float* __restrict__ w2,
                  float* __restrict__ modw,   // (M,120) sigmoid applied
                  u16*   __restrict__ fb)     // (M,64) bf16 feature table
{
    __shared__ u16 w1b[64 * 64];    // 8 KB
    __shared__ u16 w2b[64 * 128];   // 16 KB (cols 120..127 zero)
    __shared__ u16 hb[4][16 * 64];  // 8 KB, wave-private H transpose buffers

    const int tid = threadIdx.x;
    for (int i = tid; i < 64 * 64; i += 256) w1b[i] = f2bf(w1[i]);
    for (int i = tid; i < 64 * 128; i += 256) {
        int k = i >> 7, j = i & 127;
        w2b[i] = (j < 120) ? f2bf(w2[k * 120 + j]) : (u16)0;
    }
    __syncthreads();

    const int lane = tid & 63;
    const int wid  = tid >> 6;
    const int jj   = lane & 15;          // N-col / A-row within tile
    const int rb   = (lane >> 4) * 8;    // k offset within 32-wide K tile
    const int rowC = (lane >> 4) * 4;    // C/D row base

    // ---- one-time B fragments in registers ----
    bf16x8 b1f[4][2];
    #pragma unroll
    for (int nt = 0; nt < 4; ++nt)
        #pragma unroll
        for (int kk = 0; kk < 2; ++kk)
            #pragma unroll
            for (int r = 0; r < 8; ++r)
                b1f[nt][kk][r] = (short)w1b[(kk * 32 + rb + r) * 64 + nt * 16 + jj];

    bf16x8 b2f[8][2];
    #pragma unroll
    for (int nt = 0; nt < 8; ++nt)
        #pragma unroll
        for (int kk = 0; kk < 2; ++kk)
            #pragma unroll
            for (int r = 0; r < 8; ++r)
                b2f[nt][kk][r] = (short)w2b[(kk * 32 + rb + r) * 128 + nt * 16 + jj];

    float b1v[4];
    #pragma unroll
    for (int nt = 0; nt < 4; ++nt) b1v[nt] = b1[nt * 16 + jj];

    u16* hrow = &hb[wid][0];
    const int gw = blockIdx.x * 4 + wid;          // 0..999 (250 blocks)

    for (int t = gw; t < MQ / 16; t += 1000) {    // 2 tiles per wave
        const int m0 = t * 16;

        // ---- A fragments: rows m0+jj, k = rb..rb+7 and 32+rb..32+rb+7 ----
        const float* ar = s_feats + (size_t)(m0 + jj) * 64 + rb;
        float4 v0 = *(const float4*)(ar);
        float4 v1 = *(const float4*)(ar + 4);
        float4 v2 = *(const float4*)(ar + 32);
        float4 v3 = *(const float4*)(ar + 36);
        bf16x8 a0, a1;
        a0[0] = (short)f2bf(v0.x); a0[1] = (short)f2bf(v0.y);
        a0[2] = (short)f2bf(v0.z); a0[3] = (short)f2bf(v0.w);
        a0[4] = (short)f2bf(v1.x); a0[5] = (short)f2bf(v1.y);
        a0[6] = (short)f2bf(v1.z); a0[7] = (short)f2bf(v1.w);
        a1[0] = (short)f2bf(v2.x); a1[1] = (short)f2bf(v2.y);
        a1[2] = (short)f2bf(v2.z); a1[3] = (short)f2bf(v2.w);
        a1[4] = (short)f2bf(v3.x); a1[5] = (short)f2bf(v3.y);
        a1[6] = (short)f2bf(v3.z); a1[7] = (short)f2bf(v3.w);

        // bf16 feature table rows (16B vector stores)
        *(bf16x8*)(fb + (size_t)(m0 + jj) * 64 + rb)      = a0;
        *(bf16x8*)(fb + (size_t)(m0 + jj) * 64 + 32 + rb) = a1;

        // ---- GEMM1: H = leaky(F @ W1 + b1) ----
        f32x4 acc[4];
        #pragma unroll
        for (int nt = 0; nt < 4; ++nt) {
            f32x4 z = {0.f, 0.f, 0.f, 0.f};
            z = __builtin_amdgcn_mfma_f32_16x16x32_bf16(a0, b1f[nt][0], z, 0, 0, 0);
            acc[nt] = __builtin_amdgcn_mfma_f32_16x16x32_bf16(a1, b1f[nt][1], z, 0, 0, 0);
        }
        // epilogue1 + transpose through wave-private LDS
        #pragma unroll
        for (int nt = 0; nt < 4; ++nt) {
            #pragma unroll
            for (int r = 0; r < 4; ++r) {
                float h = acc[nt][r] + b1v[nt];
                h = (h >= 0.f) ? h : 0.1f * h;
                hrow[(rowC + r) * 64 + nt * 16 + jj] = f2bf(h);
            }
        }
        bf16x8 ha0 = *(bf16x8*)(hrow + jj * 64 + rb);        // row=jj, k=rb..
        bf16x8 ha1 = *(bf16x8*)(hrow + jj * 64 + 32 + rb);

        // ---- GEMM2 + sigmoid + store ----
        #pragma unroll
        for (int nt = 0; nt < 8; ++nt) {
            f32x4 z = {0.f, 0.f, 0.f, 0.f};
            z = __builtin_amdgcn_mfma_f32_16x16x32_bf16(ha0, b2f[nt][0], z, 0, 0, 0);
            f32x4 c2 = __builtin_amdgcn_mfma_f32_16x16x32_bf16(ha1, b2f[nt][1], z, 0, 0, 0);
            const int j = nt * 16 + jj;
            if (j < 120) {
                #pragma unroll
                for (int r = 0; r < 4; ++r)
                    modw[(size_t)(m0 + rowC + r) * 120 + j] =
                        1.f / (1.f + __expf(-c2[r]));
            }
        }
    }
}

// ---------------------------------------------------------------- phase 2 (bf16 gather)
__global__ __launch_bounds__(256, 4)
void kp_gather_bf16(const float* __restrict__ q_pts,
                    const float* __restrict__ s_pts,
                    const u16*   __restrict__ fb,
                    const int*   __restrict__ neighb_inds,
                    const float* __restrict__ kpts,
                    const float* __restrict__ weights,
                    const float* __restrict__ modw,
                    float* __restrict__ out)
{
    __shared__ float wt_lds[15 * 64];
    const int tid = threadIdx.x;
    if (tid < 240) ((float4*)wt_lds)[tid] = ((const float4*)weights)[tid];
    __syncthreads();

    const int lane = tid & 63;
    const int wid  = tid >> 6;
    const int c    = lane;
    const int u    = c >> 3;
    const int pair = blockIdx.x * 4 + wid;   // 16000 pairs exactly
    const int m0 = pair * 2;

    // ---- influence: lane = q*32 + h ----
    const int q = lane >> 5;
    const int m = m0 + q;
    const int ind = neighb_inds[(size_t)m0 * 32 + lane];
    const float qx = q_pts[m * 3 + 0];
    const float qy = q_pts[m * 3 + 1];
    const float qz = q_pts[m * 3 + 2];
    const float px = s_pts[(size_t)ind * 3 + 0] - qx;
    const float py = s_pts[(size_t)ind * 3 + 1] - qy;
    const float pz = s_pts[(size_t)ind * 3 + 2] - qz;
    float best = 1e30f; int bk = 0;
    #pragma unroll
    for (int k = 0; k < 15; ++k) {
        float ex = px - kpts[k * 3 + 0];
        float ey = py - kpts[k * 3 + 1];
        float ez = pz - kpts[k * 3 + 2];
        float d2 = fmaf(ex, ex, fmaf(ey, ey, ez * ez));
        if (d2 < best) { best = d2; bk = k; }   // first-min (argmin rule)
    }
    const float infl = fmaxf(0.f, 1.f - sqrtf(best));
    const int pk = (ind << 4) | bk;

    // ---- modulation rows ----
    const size_t mb0 = (size_t)m0 * 120, mb1 = mb0 + 120;
    const float vA0 = modw[mb0 + c];
    const float vB0 = (c < 56) ? modw[mb0 + 64 + c] : 0.f;
    const float vA1 = modw[mb1 + c];
    const float vB1 = (c < 56) ? modw[mb1 + 64 + c] : 0.f;

    // ---- deep-batched bf16 gathers (pure loads, readlane addressing) ----
    u16 ga[32], gb[32];
    #pragma unroll
    for (int h = 0; h < 32; ++h)
        ga[h] = fb[(size_t)(rli(pk, h) >> 4) * 64 + c];
    #pragma unroll
    for (int h = 0; h < 32; ++h)
        gb[h] = fb[(size_t)(rli(pk, 32 + h) >> 4) * 64 + c];

    // ---- reduce query m0 ----
    float p0 = 0.f, p1 = 0.f, p2 = 0.f, p3 = 0.f;
    #pragma unroll
    for (int h = 0; h < 32; h += 4) {
        #pragma unroll
        for (int j = 0; j < 4; ++j) {
            const int s = rli(pk, h + j);
            const int kh = s & 15;
            const float fl = rlf(infl, h + j);
            const float sv = (kh < 8) ? __shfl(vA0, (kh << 3) + u)
                                      : __shfl(vB0, ((kh - 8) << 3) + u);
            const float w = wt_lds[(kh << 6) + c] * sv * fl;
            float& p = (j == 0) ? p0 : (j == 1) ? p1 : (j == 2) ? p2 : p3;
            p = fmaf(bf2f(ga[h + j]), w, p);
        }
    }
    const float acc0 = (p0 + p1) + (p2 + p3);

    // ---- reduce query m0+1 ----
    float r0 = 0.f, r1 = 0.f, r2 = 0.f, r3 = 0.f;
    #pragma unroll
    for (int h = 0; h < 32; h += 4) {
        #pragma unroll
        for (int j = 0; j < 4; ++j) {
            const int s = rli(pk, 32 + h + j);
            const int kh = s & 15;
            const float fl = rlf(infl, 32 + h + j);
            const float sv = (kh < 8) ? __shfl(vA1, (kh << 3) + u)
                                      : __shfl(vB1, ((kh - 8) << 3) + u);
            const float w = wt_lds[(kh << 6) + c] * sv * fl;
            float& p = (j == 0) ? r0 : (j == 1) ? r1 : (j == 2) ? r2 : r3;
            p = fmaf(bf2f(gb[h + j]), w, p);
        }
    }
    const float acc1 = (r0 + r1) + (r2 + r3);

    out[(size_t)m0 * 64 + c]       = acc0;
    out[(size_t)(m0 + 1) * 64 + c] = acc1;
}

// ------------------- fallback tier: round-3/4 proven f32 path -------------------
__global__ __launch_bounds__(256, 3)
void mod_mlp(const float* __restrict__ s_feats,
             const float* __restrict__ w1,
             const float* __restrict__ b1,
             const float* __restrict__ w2,
             float* __restrict__ modw)
{
    __shared__ float w1_lds[64 * 64];
    __shared__ float w2_lds[64 * 120 + 8];

    const int tid = threadIdx.x;
    {
        const float4* s1 = (const float4*)w1;
        float4* d1 = (float4*)w1_lds;
        #pragma unroll
        for (int i = 0; i < 4; ++i) d1[tid + 256 * i] = s1[tid + 256 * i];
        const float4* s2 = (const float4*)w2;
        float4* d2 = (float4*)w2_lds;
        for (int i = tid; i < (64 * 120) / 4; i += 256) d2[i] = s2[i];
        if (tid < 8) w2_lds[64 * 120 + tid] = 0.f;
    }
    __syncthreads();

    const int lane = tid & 63;
    const int wid  = tid >> 6;
    const int c    = lane;
    const int nwaves = gridDim.x * 4;
    const int gwave  = blockIdx.x * 4 + wid;
    const float b1v = b1[c];
    const int cB = 64 + ((c < 56) ? c : 55);

    for (int pair = gwave; pair * 2 < MQ; pair += nwaves) {
        const int m0 = pair * 2;
        float f0 = s_feats[(size_t)m0 * 64 + c];
        float f1 = s_feats[(size_t)(m0 + 1) * 64 + c];
        float h0a = b1v, h0b = 0.f, h1a = b1v, h1b = 0.f;
        #pragma unroll
        for (int i = 0; i < 64; i += 2) {
            float wa = w1_lds[i * 64 + c];
            float wb = w1_lds[(i + 1) * 64 + c];
            h0a = fmaf(rlf(f0, i), wa, h0a);
            h0b = fmaf(rlf(f0, i + 1), wb, h0b);
            h1a = fmaf(rlf(f1, i), wa, h1a);
            h1b = fmaf(rlf(f1, i + 1), wb, h1b);
        }
        float h0 = h0a + h0b, h1 = h1a + h1b;
        h0 = (h0 >= 0.f) ? h0 : 0.1f * h0;
        h1 = (h1 >= 0.f) ? h1 : 0.1f * h1;
        float a00 = 0.f, a01 = 0.f, a10 = 0.f, a11 = 0.f;
        #pragma unroll
        for (int i = 0; i < 64; ++i) {
            float wA = w2_lds[i * 120 + c];
            float wB = w2_lds[i * 120 + cB];
            float s0 = rlf(h0, i);
            float s1 = rlf(h1, i);
            a00 = fmaf(s0, wA, a00);
            a01 = fmaf(s0, wB, a01);
            a10 = fmaf(s1, wA, a10);
            a11 = fmaf(s1, wB, a11);
        }
        modw[(size_t)m0 * 120 + c]       = 1.f / (1.f + __expf(-a00));
        modw[(size_t)(m0 + 1) * 120 + c] = 1.f / (1.f + __expf(-a10));
        if (c < 56) {
            modw[(size_t)m0 * 120 + 64 + c]       = 1.f / (1.f + __expf(-a01));
            modw[(size_t)(m0 + 1) * 120 + 64 + c] = 1.f / (1.f + __expf(-a11));
        }
    }
}

__global__ __launch_bounds__(256, 4)
void kp_gather(const float* __restrict__ q_pts,
               const float* __restrict__ s_pts,
               const float* __restrict__ s_feats,
               const int*   __restrict__ neighb_inds,
               const float* __restrict__ kpts,
               const float* __restrict__ weights,
               const float* __restrict__ modw,
               float* __restrict__ out)
{
    __shared__ float wt_lds[15 * 64];
    const int tid = threadIdx.x;
    if (tid < 240) ((float4*)wt_lds)[tid] = ((const float4*)weights)[tid];
    __syncthreads();

    const int lane = tid & 63;
    const int wid  = tid >> 6;
    const int c    = lane;
    const int u    = c >> 3;
    const int pair = blockIdx.x * 4 + wid;
    const int m0 = pair * 2;

    const int q = lane >> 5;
    const int m = m0 + q;
    const int ind = neighb_inds[(size_t)m0 * 32 + lane];
    const float qx = q_pts[m * 3 + 0];
    const float qy = q_pts[m * 3 + 1];
    const float qz = q_pts[m * 3 + 2];
    const float px = s_pts[(size_t)ind * 3 + 0] - qx;
    const float py = s_pts[(size_t)ind * 3 + 1] - qy;
    const float pz = s_pts[(size_t)ind * 3 + 2] - qz;
    float best = 1e30f; int bk = 0;
    #pragma unroll
    for (int k = 0; k < 15; ++k) {
        float ex = px - kpts[k * 3 + 0];
        float ey = py - kpts[k * 3 + 1];
        float ez = pz - kpts[k * 3 + 2];
        float d2 = fmaf(ex, ex, fmaf(ey, ey, ez * ez));
        if (d2 < best) { best = d2; bk = k; }
    }
    const float infl = fmaxf(0.f, 1.f - sqrtf(best));
    const int pk = (ind << 4) | bk;

    const size_t mb0 = (size_t)m0 * 120, mb1 = mb0 + 120;
    const float vA0 = modw[mb0 + c];
    const float vB0 = (c < 56) ? modw[mb0 + 64 + c] : 0.f;
    const float vA1 = modw[mb1 + c];
    const float vB1 = (c < 56) ? modw[mb1 + 64 + c] : 0.f;

    float fv0[32], fv1[32];
    #pragma unroll
    for (int h = 0; h < 32; ++h)
        fv0[h] = s_feats[(size_t)(rli(pk, h) >> 4) * 64 + c];
    #pragma unroll
    for (int h = 0; h < 32; ++h)
        fv1[h] = s_feats[(size_t)(rli(pk, 32 + h) >> 4) * 64 + c];

    float p0 = 0.f, p1 = 0.f, p2 = 0.f, p3 = 0.f;
    #pragma unroll
    for (int h = 0; h < 32; h += 4) {
        #pragma unroll
        for (int j = 0; j < 4; ++j) {
            const int s = rli(pk, h + j);
            const int kh = s & 15;
            const float fl = rlf(infl, h + j);
            const float sv = (kh < 8) ? __shfl(vA0, (kh << 3) + u)
                                      : __shfl(vB0, ((kh - 8) << 3) + u);
            const float w = wt_lds[(kh << 6) + c] * sv * fl;
            float& p = (j == 0) ? p0 : (j == 1) ? p1 : (j == 2) ? p2 : p3;
            p = fmaf(fv0[h + j], w, p);
        }
    }
    const float acc0 = (p0 + p1) + (p2 + p3);

    float r0 = 0.f, r1 = 0.f, r2 = 0.f, r3 = 0.f;
    #pragma unroll
    for (int h = 0; h < 32; h += 4) {
        #pragma unroll
        for (int j = 0; j < 4; ++j) {
            const int s = rli(pk, 32 + h + j);
            const int kh = s & 15;
            const float fl = rlf(infl, 32 + h + j);
            const float sv = (kh < 8) ? __shfl(vA1, (kh << 3) + u)
                                      : __shfl(vB1, ((kh - 8) << 3) + u);
            const float w = wt_lds[(kh << 6) + c] * sv * fl;
            float& p = (j == 0) ? r0 : (j == 1) ? r1 : (j == 2) ? r2 : r3;
            p = fmaf(fv1[h + j], w, p);
        }
    }
    const float acc1 = (r0 + r1) + (r2 + r3);

    out[(size_t)m0 * 64 + c]       = acc0;
    out[(size_t)(m0 + 1) * 64 + c] = acc1;
}

extern "C" void kernel_launch(void* const* d_in, const int* in_sizes, int n_in,
                              void* d_out, int out_size, void* d_ws, size_t ws_size,
                              hipStream_t stream) {
    const float* q_pts       = (const float*)d_in[0];
    const float* s_pts       = (const float*)d_in[1];
    const float* s_feats     = (const float*)d_in[2];
    const int*   neighb_inds = (const int*)d_in[3];
    const float* kpts        = (const float*)d_in[4];
    const float* weights     = (const float*)d_in[5];
    const float* w1          = (const float*)d_in[6];
    const float* b1          = (const float*)d_in[7];
    const float* w2          = (const float*)d_in[8];
    float* out = (float*)d_out;

    const size_t needFB   = (size_t)MQ * 64 * sizeof(u16);     // 4.096 MB
    const size_t needMODW = (size_t)MQ * 120 * sizeof(float);  // 15.36 MB
    if (ws_size >= needFB + needMODW) {
        u16*   fb   = (u16*)d_ws;
        float* modw = (float*)((char*)d_ws + needFB);
        mod_mlp_mfma<<<250, 256, 0, stream>>>(s_feats, w1, b1, w2, modw, fb);
        kp_gather_bf16<<<MQ / 8, 256, 0, stream>>>(q_pts, s_pts, fb, neighb_inds,
                                                   kpts, weights, modw, out);
    } else {
        float* modw = (float*)d_ws;
        mod_mlp<<<768, 256, 0, stream>>>(s_feats, w1, b1, w2, modw);
        kp_gather<<<MQ / 8, 256, 0, stream>>>(q_pts, s_pts, s_feats, neighb_inds,
                                              kpts, weights, modw, out);
    }
}